// Round 23
// baseline (123.496 us; speedup 1.0000x reference)
//
#include <hip/hip_runtime.h>
#include <cstdint>
#include <cstddef>

// Problem dims (compile-time)
#define B_DIM 2
#define L_DIM 2048
#define E_DIM 1024
#define H_DIM 16
#define HD    64
#define M_ROWS (B_DIM * L_DIM)   // 4096
#define QKV_N  (3 * E_DIM)       // 3072
#define C_CONST 2.01f
#define NCH_BH 40                // chunks per bh at QBLK=128
#define LOG2E 1.4426950408889634f
#define LN2   0.6931471805599453f

typedef unsigned short ushort_t;
typedef __attribute__((ext_vector_type(8))) short bf16x8;
typedef __attribute__((ext_vector_type(4))) float f32x4;

__device__ __forceinline__ unsigned int f2bf(float f) {
    union { float f; unsigned int u; } v; v.f = f;
    return (v.u + 0x7FFFu + ((v.u >> 16) & 1u)) >> 16;   // RNE
}
__device__ __forceinline__ float bf2f_lo(unsigned int u) {
    union { unsigned int u; float f; } v; v.u = u << 16; return v.f;
}
__device__ __forceinline__ float bf2f_hi(unsigned int u) {
    union { unsigned int u; float f; } v; v.u = u & 0xffff0000u; return v.f;
}

__device__ __forceinline__ void gload16(const void* g, void* l) {
    __builtin_amdgcn_global_load_lds(
        (const __attribute__((address_space(1))) void*)g,
        (__attribute__((address_space(3))) void*)l, 16, 0, 0);
}

// ---------------------------------------------------------------------------
// prep: merged cast(x->bf16) + transpose(Wqkv) + transpose(Wout).
// ---------------------------------------------------------------------------
__device__ __forceinline__ void transpose_tile_dev(
    const float* __restrict__ in, ushort_t* __restrict__ out,
    int R, int Cn, int c0, int r0, int tid, float t[64][65])
{
    for (int idx = tid; idx < 4096; idx += 256) {
        const int r = idx >> 6, c = idx & 63;
        t[r][c] = in[(size_t)(r0 + r) * Cn + c0 + c];
    }
    __syncthreads();
    for (int idx = tid; idx < 4096; idx += 256) {
        const int c = idx >> 6, r = idx & 63;
        out[(size_t)(c0 + c) * R + r0 + r] = (ushort_t)f2bf(t[r][c]);
    }
}

__global__ __launch_bounds__(256) void prep_kernel(
    const float* __restrict__ x, ushort_t* __restrict__ xb,
    const float* __restrict__ Wqkv, ushort_t* __restrict__ WqkvT,
    const float* __restrict__ Wout, ushort_t* __restrict__ WoutT)
{
    __shared__ float t[64][65];
    const int bx = blockIdx.x;
    const int tid = threadIdx.x;
    if (bx < 4096) {
        const int i = bx * 256 + tid;
        const float4 v = ((const float4*)x)[i];
        uint2 p;
        p.x = f2bf(v.x) | (f2bf(v.y) << 16);
        p.y = f2bf(v.z) | (f2bf(v.w) << 16);
        ((uint2*)xb)[i] = p;
    } else if (bx < 4096 + 768) {
        const int idx = bx - 4096;
        transpose_tile_dev(Wqkv, WqkvT, E_DIM, QKV_N, (idx % 48) * 64, (idx / 48) * 64, tid, t);
    } else {
        const int idx = bx - 4864;
        transpose_tile_dev(Wout, WoutT, E_DIM, E_DIM, (idx & 15) * 64, (idx >> 4) * 64, tid, t);
    }
}

// ---------------------------------------------------------------------------
// bf16 MFMA GEMM, 128x128 tile, BK=32, 4 waves, 2-phase with REORDERED
// hazard chain: (1) ds_read fragments from buf[cur] FIRST (no pending loads
// -> no vmcnt wait), (2) issue next-tile global_load_lds into buf[cur^1]
// (after reads in program order -> compiler inserts no wait), (3) MFMA
// overlaps in-flight loads, (4) __syncthreads drains. Fixes r14's failure
// (loads-before-reads forced a conservative vmcnt before every ds_read).
// Accumulation order identical to r13/r17/r22 -> bit-identical output.
// MODE 0: qkv; epilogue: q,k L2-normalized -> bf16 [bh][l][d];
//         v -> bf16 V^T [bh][d][key] directly.
// MODE 1: plain C+bias fp32 [M][E].
// ---------------------------------------------------------------------------
template<int NCOLS, int MODE>
__global__ __launch_bounds__(256) void gemm_bt_kernel(
    const ushort_t* __restrict__ A, const ushort_t* __restrict__ BT,
    const float* __restrict__ bias, float* __restrict__ outf,
    ushort_t* __restrict__ q16, ushort_t* __restrict__ k16,
    ushort_t* __restrict__ vt16)
{
    __shared__ __align__(16) ushort_t Abuf[2][128 * 32];
    __shared__ __align__(16) ushort_t Bbuf[2][128 * 32];
    const int tid = threadIdx.x;
    const int wave = tid >> 6, lane = tid & 63;
    const int m0 = blockIdx.x * 128, n0 = blockIdx.y * 128;
    const int wr = (wave >> 1) * 64, wc = (wave & 1) * 64;
    const int g = lane >> 4, l15 = lane & 15;

    f32x4 acc[4][4];
    #pragma unroll
    for (int i = 0; i < 4; ++i)
        #pragma unroll
        for (int j = 0; j < 4; ++j) acc[i][j] = f32x4{0.f, 0.f, 0.f, 0.f};

    const int sr = tid >> 2;
    const int sc = (tid & 3) * 8;
    const ushort_t* Asrc0 = A + (size_t)(m0 + sr) * 1024 + sc;
    const ushort_t* Asrc1 = A + (size_t)(m0 + 64 + sr) * 1024 + sc;
    const ushort_t* Bsrc0 = BT + (size_t)(n0 + sr) * 1024 + sc;
    const ushort_t* Bsrc1 = BT + (size_t)(n0 + 64 + sr) * 1024 + sc;

    // prologue: stage k0=0 into buffer 0
    gload16(Asrc0, &Abuf[0][tid * 8]);
    gload16(Asrc1, &Abuf[0][2048 + tid * 8]);
    gload16(Bsrc0, &Bbuf[0][tid * 8]);
    gload16(Bsrc1, &Bbuf[0][2048 + tid * 8]);
    __syncthreads();

    for (int k0 = 0; k0 < 1024; k0 += 32) {
        const int cur = (k0 >> 5) & 1;

        // (1) read all fragments from current buffer FIRST
        bf16x8 af[4], bfv[4];
        #pragma unroll
        for (int mt = 0; mt < 4; ++mt)
            af[mt] = *(const bf16x8*)&Abuf[cur][(wr + mt * 16 + l15) * 32 + 8 * g];
        #pragma unroll
        for (int nt = 0; nt < 4; ++nt)
            bfv[nt] = *(const bf16x8*)&Bbuf[cur][(wc + nt * 16 + l15) * 32 + 8 * g];

        // (2) issue next tile's staging into the other buffer
        if (k0 + 32 < 1024) {
            gload16(Asrc0 + k0 + 32, &Abuf[cur ^ 1][tid * 8]);
            gload16(Asrc1 + k0 + 32, &Abuf[cur ^ 1][2048 + tid * 8]);
            gload16(Bsrc0 + k0 + 32, &Bbuf[cur ^ 1][tid * 8]);
            gload16(Bsrc1 + k0 + 32, &Bbuf[cur ^ 1][2048 + tid * 8]);
        }

        // (3) MFMA (register-only) overlaps in-flight loads
        #pragma unroll
        for (int nt = 0; nt < 4; ++nt)
            #pragma unroll
            for (int mt = 0; mt < 4; ++mt)
                acc[mt][nt] = __builtin_amdgcn_mfma_f32_16x16x32_bf16(af[mt], bfv[nt], acc[mt][nt], 0, 0, 0);

        __syncthreads();   // (4) drains staging (vmcnt 0) + releases cur
    }

    if (MODE == 0) {
        const int nBase = n0 + wc;
        const int sel = nBase >> 10;            // 0=q 1=k 2=v
        const int h   = (nBase & 1023) >> 6;
        float bv[4];
        #pragma unroll
        for (int nt = 0; nt < 4; ++nt) bv[nt] = bias[nBase + nt * 16 + l15];

        if (sel <= 1) {
            ushort_t* dst16 = (sel == 0) ? q16 : k16;
            #pragma unroll
            for (int mt = 0; mt < 4; ++mt) {
                float val[4][4], ss[4] = {0.f, 0.f, 0.f, 0.f};
                #pragma unroll
                for (int nt = 0; nt < 4; ++nt)
                    #pragma unroll
                    for (int r = 0; r < 4; ++r) {
                        const float v = acc[mt][nt][r] + bv[nt];
                        val[nt][r] = v;
                        ss[r] = fmaf(v, v, ss[r]);
                    }
                #pragma unroll
                for (int r = 0; r < 4; ++r) {
                    float t = ss[r];
                    t += __shfl_xor(t, 1); t += __shfl_xor(t, 2);
                    t += __shfl_xor(t, 4); t += __shfl_xor(t, 8);
                    ss[r] = 1.0f / sqrtf(t);
                }
                #pragma unroll
                for (int r = 0; r < 4; ++r) {
                    const int m = m0 + wr + mt * 16 + 4 * g + r;
                    const int bb = m >> 11, ll = m & 2047;
                    ushort_t* base = dst16 + ((size_t)((bb * H_DIM + h) * L_DIM + ll)) * HD + l15;
                    #pragma unroll
                    for (int nt = 0; nt < 4; ++nt)
                        base[nt * 16] = (ushort_t)f2bf(val[nt][r] * ss[r]);
                }
            }
        } else {
            // write V^T directly: vt16[(bb*H+h)*HD + d][key], 4 keys/store
            const int bb = m0 >> 11;
            #pragma unroll
            for (int nt = 0; nt < 4; ++nt) {
                const int d = nt * 16 + l15;
                ushort_t* vbase = vt16 + ((size_t)((bb * H_DIM + h) * HD + d)) * L_DIM;
                #pragma unroll
                for (int mt = 0; mt < 4; ++mt) {
                    const int key = (m0 & 2047) + wr + mt * 16 + 4 * g;
                    const float v0 = acc[mt][nt][0] + bv[nt];
                    const float v1 = acc[mt][nt][1] + bv[nt];
                    const float v2 = acc[mt][nt][2] + bv[nt];
                    const float v3 = acc[mt][nt][3] + bv[nt];
                    uint2 pk;
                    asm("v_cvt_pk_bf16_f32 %0, %1, %2" : "=v"(pk.x) : "v"(v0), "v"(v1));
                    asm("v_cvt_pk_bf16_f32 %0, %1, %2" : "=v"(pk.y) : "v"(v2), "v"(v3));
                    *(uint2*)&vbase[key] = pk;
                }
            }
        }
    } else {
        #pragma unroll
        for (int nt = 0; nt < 4; ++nt) {
            const int n = n0 + wc + nt * 16 + l15;
            const float bvv = bias[n];
            #pragma unroll
            for (int mt = 0; mt < 4; ++mt)
                #pragma unroll
                for (int r = 0; r < 4; ++r) {
                    const int m = m0 + wr + mt * 16 + 4 * g + r;
                    outf[(size_t)m * E_DIM + n] = acc[mt][nt][r] + bvv;
                }
        }
    }
}

// ---------------------------------------------------------------------------
// Split-K MFMA flash attention, QBLK=128, 8 waves (512 thr), kv tile 64.
// LPT dispatch (heavy chunks first). Log2-domain fixed-shift softmax.
// (unchanged measured version)
// ---------------------------------------------------------------------------
__global__ __launch_bounds__(512) void attn_mfma_kernel(
    const ushort_t* __restrict__ qn, const ushort_t* __restrict__ kn,
    const ushort_t* __restrict__ vt,
    ushort_t* __restrict__ pO, float* __restrict__ pl, float* __restrict__ pm)
{
    __shared__ __align__(16) ushort_t Qs[128 * 64];     // Q; reused as P
    __shared__ __align__(16) ushort_t Ks[2][64 * 64];
    __shared__ __align__(16) ushort_t Vs[2][64 * 64];

    // LPT: reverse dispatch order (heavy qtp first); decode chunk -> (qt', s)
    const int cD = NCH_BH - 1 - blockIdx.x;
    int c = cD, qtp = 0, s = 0;
    #pragma unroll
    for (int gg = 0; gg < 4; ++gg) {
        const int sz = 4 * (gg + 1);
        if (c < sz) { qtp = 4 * gg + c / (gg + 1); s = c - (c / (gg + 1)) * (gg + 1); break; }
        c -= sz;
    }
    const int bh = blockIdx.y;
    const int cid = bh * NCH_BH + cD;
    const int q0 = qtp * 128;
    const int kt0 = 8 * s;
    const int ktEnd = min(8 * s + 8, 2 * qtp + 2);

    const int tid = threadIdx.x, w = tid >> 6, lane = tid & 63;
    const int g = lane >> 4, l15 = lane & 15;
    ushort_t* Pw = &Qs[w * 16 * 64];                // wave's own dead Q rows

    const ushort_t* Qg = qn + ((size_t)bh * L_DIM + q0) * HD;
    const ushort_t* Kg = kn + (size_t)bh * L_DIM * HD;
    const ushort_t* Vg = vt + (size_t)bh * HD * L_DIM;

    const int srow = tid >> 3, sch = tid & 7;
    const int qr2 = (tid + 512) >> 3, qc2 = (tid + 512) & 7;

    {
        const int j0 = kt0 * 64;
        gload16(Qg + srow * 64 + ((sch ^ (srow & 7)) << 3), Qs + srow * 64 + (sch << 3));
        gload16(Qg + qr2 * 64 + ((qc2 ^ (qr2 & 7)) << 3), Qs + qr2 * 64 + (qc2 << 3));
        gload16(Kg + (size_t)(j0 + srow) * 64 + ((sch ^ (srow & 7)) << 3), Ks[0] + srow * 64 + (sch << 3));
        gload16(Vg + (size_t)srow * L_DIM + j0 + ((sch ^ (srow & 7)) << 3), Vs[0] + srow * 64 + (sch << 3));
    }
    __syncthreads();

    bf16x8 qf[2];
    #pragma unroll
    for (int kc = 0; kc < 2; ++kc) {
        const int row = 16 * w + l15;
        qf[kc] = *(const bf16x8*)&Qs[row * 64 + (((4 * kc + g) ^ (row & 7)) << 3)];
    }

    f32x4 o[4];
    float M = 8.0f * LOG2E, l_i = 0.f;
    #pragma unroll
    for (int j = 0; j < 4; ++j) o[j] = f32x4{0.f, 0.f, 0.f, 0.f};

    const int qrow = q0 + 16 * w + l15;
    const float DC0 = 1.39322583292549f;      // C_CONST * ln2
    const float DC1 = -1.3862943611198906f;   // -2 * ln2

    for (int kt = kt0; kt < ktEnd; ++kt) {
        const int cur = (kt - kt0) & 1;
        if (kt + 1 < ktEnd) {
            const int j1 = (kt + 1) * 64;
            gload16(Kg + (size_t)(j1 + srow) * 64 + ((sch ^ (srow & 7)) << 3),
                    Ks[cur ^ 1] + srow * 64 + (sch << 3));
            gload16(Vg + (size_t)srow * L_DIM + j1 + ((sch ^ (srow & 7)) << 3),
                    Vs[cur ^ 1] + srow * 64 + (sch << 3));
        }
        const int j0 = kt * 64;

        // ---- S^T = K . Q^T ----
        bf16x8 ak[4][2];
        #pragma unroll
        for (int kt4 = 0; kt4 < 4; ++kt4)
            #pragma unroll
            for (int kc = 0; kc < 2; ++kc) {
                const int row = 16 * kt4 + l15;
                ak[kt4][kc] = *(const bf16x8*)&Ks[cur][row * 64 + (((4 * kc + g) ^ (row & 7)) << 3)];
            }
        f32x4 st[4];
        #pragma unroll
        for (int kt4 = 0; kt4 < 4; ++kt4) st[kt4] = f32x4{0.f, 0.f, 0.f, 0.f};
        __builtin_amdgcn_s_setprio(1);
        #pragma unroll
        for (int kc = 0; kc < 2; ++kc)
            #pragma unroll
            for (int kt4 = 0; kt4 < 4; ++kt4)
                st[kt4] = __builtin_amdgcn_mfma_f32_16x16x32_bf16(
                    ak[kt4][kc], qf[kc], st[kt4], 0, 0, 0);
        __builtin_amdgcn_s_setprio(0);

        // ---- score -> e (log2 domain, shifted by M); in-lane max ----
        const float negM = -M;
        float emax = -1e30f;
        #pragma unroll
        for (int kt4 = 0; kt4 < 4; ++kt4)
            #pragma unroll
            for (int r = 0; r < 4; ++r) {
                const float x = st[kt4][r];
                const float d = fmaf(DC1, x, DC0);
                float rr;
                asm("v_rcp_f32 %0, %1" : "=v"(rr) : "v"(d));
                const float e = fmaf(x * x, rr, negM);
                st[kt4][r] = e;
                emax = fmaxf(emax, e);
            }

        if (kt >= 2 * qtp) {   // diagonal region: mask, redo emax
            emax = -1e30f;
            #pragma unroll
            for (int kt4 = 0; kt4 < 4; ++kt4)
                #pragma unroll
                for (int r = 0; r < 4; ++r) {
                    const int key = j0 + 16 * kt4 + 4 * g + r;
                    float e = st[kt4][r];
                    e = (key > qrow) ? -100.f : e;
                    st[kt4][r] = e;
                    emax = fmaxf(emax, e);
                }
        }

        if (__any(emax > 0.f)) {
            float rm = fmaxf(emax, __shfl_xor(emax, 16));
            rm = fmaxf(rm, __shfl_xor(rm, 32));
            rm = fmaxf(rm, 0.f);
            #pragma unroll
            for (int kt4 = 0; kt4 < 4; ++kt4)
                #pragma unroll
                for (int r = 0; r < 4; ++r) st[kt4][r] -= rm;
            const float nrm = -rm;
            float scl;
            asm("v_exp_f32 %0, %1" : "=v"(scl) : "v"(nrm));
            l_i *= scl;
            #pragma unroll
            for (int r = 0; r < 4; ++r) {
                const float sv = __shfl(scl, 4 * g + r);
                #pragma unroll
                for (int dt = 0; dt < 4; ++dt) o[dt][r] *= sv;
            }
            M += rm;
        }

        // ---- p = exp2(e); per-lane partial sum; pack via cvt_pk ----
        float ts = 0.f;
        #pragma unroll
        for (int kt4 = 0; kt4 < 4; ++kt4) {
            const float e0 = st[kt4][0], e1 = st[kt4][1];
            const float e2 = st[kt4][2], e3 = st[kt4][3];
            float p0, p1, p2, p3;
            asm("v_exp_f32 %0, %1" : "=v"(p0) : "v"(e0));
            asm("v_exp_f32 %0, %1" : "=v"(p1) : "v"(e1));
            asm("v_exp_f32 %0, %1" : "=v"(p2) : "v"(e2));
            asm("v_exp_f32 %0, %1" : "=v"(p3) : "v"(e3));
            ts += (p0 + p1) + (p2 + p3);
            uint2 pk;
            asm("v_cvt_pk_bf16_f32 %0, %1, %2" : "=v"(pk.x) : "v"(p0), "v"(p1));
            asm("v_cvt_pk_bf16_f32 %0, %1, %2" : "=v"(pk.y) : "v"(p2), "v"(p3));
            const int ch = 2 * kt4 + (g >> 1);
            *(uint2*)&Pw[l15 * 64 + ((ch ^ (l15 & 7)) << 3) + 4 * (g & 1)] = pk;
        }
        l_i += ts;

        // ---- O += P . V ----
        bf16x8 ap[2], av[4][2];
        #pragma unroll
        for (int kc = 0; kc < 2; ++kc)
            ap[kc] = *(const bf16x8*)&Pw[l15 * 64 + (((4 * kc + g) ^ (l15 & 7)) << 3)];
        #pragma unroll
        for (int dt = 0; dt < 4; ++dt)
            #pragma unroll
            for (int kc = 0; kc < 2; ++kc) {
                const int row = 16 * dt + l15;
                av[dt][kc] = *(const bf16x8*)&Vs[cur][row * 64 + (((4 * kc + g) ^ (row & 7)) << 3)];
            }
        __builtin_amdgcn_s_setprio(1);
        #pragma unroll
        for (int kc = 0; kc < 2; ++kc)
            #pragma unroll
            for (int dt = 0; dt < 4; ++dt)
                o[dt] = __builtin_amdgcn_mfma_f32_16x16x32_bf16(
                    ap[kc], av[dt][kc], o[dt], 0, 0, 0);
        __builtin_amdgcn_s_setprio(0);

        __syncthreads();
    }

    // ---- epilogue: write partials; pm in natural-log domain ----
    l_i += __shfl_xor(l_i, 16);
    l_i += __shfl_xor(l_i, 32);
    ushort_t* po = pO + (size_t)cid * 8192 + (16 * w) * 64;
    #pragma unroll
    for (int r = 0; r < 4; ++r)
        #pragma unroll
        for (int dt = 0; dt < 4; ++dt)
            po[(4 * g + r) * 64 + 16 * dt + l15] = (ushort_t)f2bf(o[dt][r]);
    if (lane < 16) {
        pl[cid * 128 + 16 * w + lane] = l_i;
        pm[cid * 128 + 16 * w + lane] = M * LN2;
    }
}

// ---------------------------------------------------------------------------
// combine: merge <=4 chunk partials per 64-row output tile; write cb bf16
// ---------------------------------------------------------------------------
__global__ __launch_bounds__(256) void combine_kernel(
    const ushort_t* __restrict__ pO, const float* __restrict__ pl,
    const float* __restrict__ pm, ushort_t* __restrict__ cb)
{
    const int qt2 = blockIdx.x, bh = blockIdx.y;
    const int qtp = qt2 >> 1, half = qt2 & 1;
    const int gg = qtp >> 2, ns = gg + 1;
    const int cid0 = bh * NCH_BH + 2 * gg * (gg + 1) + (qtp & 3) * ns;
    const int tid = threadIdx.x;
    const int row = tid >> 2, seg = tid & 3;
    const int rowc = half * 64 + row;

    float mt = -1e30f;
    for (int s2 = 0; s2 < ns; ++s2)
        mt = fmaxf(mt, pm[(cid0 + s2) * 128 + rowc]);

    float acc[16];
    #pragma unroll
    for (int j = 0; j < 16; ++j) acc[j] = 0.f;
    float l_tot = 0.f;
    for (int s2 = 0; s2 < ns; ++s2) {
        const int cid = cid0 + s2;
        const float sc = __expf(pm[cid * 128 + rowc] - mt);
        l_tot += pl[cid * 128 + rowc] * sc;
        const ushort_t* src = pO + (size_t)cid * 8192 + rowc * 64 + seg * 16;
        const uint4 u0 = *(const uint4*)src;
        const uint4 u1 = *(const uint4*)(src + 8);
        const unsigned int uu[8] = {u0.x, u0.y, u0.z, u0.w, u1.x, u1.y, u1.z, u1.w};
        #pragma unroll
        for (int j = 0; j < 8; ++j) {
            acc[2 * j]     = fmaf(sc, bf2f_lo(uu[j]), acc[2 * j]);
            acc[2 * j + 1] = fmaf(sc, bf2f_hi(uu[j]), acc[2 * j + 1]);
        }
    }
    const float inv = 1.0f / l_tot;
    const int b = bh >> 4, h = bh & 15;
    ushort_t* dst = cb + ((size_t)(b * L_DIM + qt2 * 64 + row)) * E_DIM + h * HD + seg * 16;
    uint4 w0, w1;
    w0.x = f2bf(acc[0] * inv)  | (f2bf(acc[1] * inv) << 16);
    w0.y = f2bf(acc[2] * inv)  | (f2bf(acc[3] * inv) << 16);
    w0.z = f2bf(acc[4] * inv)  | (f2bf(acc[5] * inv) << 16);
    w0.w = f2bf(acc[6] * inv)  | (f2bf(acc[7] * inv) << 16);
    w1.x = f2bf(acc[8] * inv)  | (f2bf(acc[9] * inv) << 16);
    w1.y = f2bf(acc[10] * inv) | (f2bf(acc[11] * inv) << 16);
    w1.z = f2bf(acc[12] * inv) | (f2bf(acc[13] * inv) << 16);
    w1.w = f2bf(acc[14] * inv) | (f2bf(acc[15] * inv) << 16);
    *(uint4*)dst = w0;
    *(uint4*)(dst + 8) = w1;
}

// ---------------------------------------------------------------------------
extern "C" void kernel_launch(void* const* d_in, const int* in_sizes, int n_in,
                              void* d_out, int out_size, void* d_ws, size_t ws_size,
                              hipStream_t stream)
{
    const float* x    = (const float*)d_in[0];
    const float* Wqkv = (const float*)d_in[1];
    const float* bqkv = (const float*)d_in[2];
    const float* Wout = (const float*)d_in[3];
    const float* bout = (const float*)d_in[4];
    float* out = (float*)d_out;

    char* ws = (char*)d_ws;
    const size_t MB = 1u << 20;
    ushort_t* qn16  = (ushort_t*)(ws + 0 * MB);    // [0,8)
    ushort_t* kn16  = (ushort_t*)(ws + 8 * MB);    // [8,16)
    ushort_t* vt16  = (ushort_t*)(ws + 24 * MB);   // [24,32)
    ushort_t* xb    = (ushort_t*)(ws + 32 * MB);   // [32,40) dead after qkv gemm
    ushort_t* cb    = (ushort_t*)(ws + 32 * MB);   // reuse xb slot
    ushort_t* WqkvT = (ushort_t*)(ws + 40 * MB);   // [40,46) dead after qkv gemm
    ushort_t* pO    = (ushort_t*)(ws + 40 * MB);   // [40,60) 1280 x 16KB = 20 MB
    float*    pl    = (float*)   (ws + 60 * MB);   // [60,60.625)
    float*    pm    = (float*)   (ws + 61 * MB);   // [61,61.625)
    ushort_t* WoutT = (ushort_t*)(ws + 62 * MB);   // [62,64)

    // 1) merged prep: cast x + transpose Wqkv + transpose Wout
    prep_kernel<<<5120, 256, 0, stream>>>(x, xb, Wqkv, WqkvT, Wout, WoutT);

    // 2) qkv GEMM (2-phase, reads-before-issue) + fused normalize + V^T
    gemm_bt_kernel<QKV_N, 0><<<dim3(M_ROWS / 128, QKV_N / 128), 256, 0, stream>>>(
        xb, WqkvT, bqkv, nullptr, qn16, kn16, vt16);

    // 3) split-K MFMA flash attention (QBLK=128, 8 waves, LPT) -> partials
    attn_mfma_kernel<<<dim3(NCH_BH, B_DIM * H_DIM), 512, 0, stream>>>(qn16, kn16, vt16, pO, pl, pm);

    // 4) combine partials -> cb [M][E] bf16
    combine_kernel<<<dim3(L_DIM / 64, B_DIM * H_DIM), 256, 0, stream>>>(pO, pl, pm, cb);

    // 5) out = ctx @ W_out + b (2-phase, reads-before-issue)
    gemm_bt_kernel<E_DIM, 1><<<dim3(M_ROWS / 128, E_DIM / 128), 256, 0, stream>>>(
        cb, WoutT, bout, out, nullptr, nullptr, nullptr);
}

// Round 24
// 117.449 us; speedup vs baseline: 1.0515x; 1.0515x over previous
//
#include <hip/hip_runtime.h>
#include <cstdint>
#include <cstddef>

// Problem dims (compile-time)
#define B_DIM 2
#define L_DIM 2048
#define E_DIM 1024
#define H_DIM 16
#define HD    64
#define M_ROWS (B_DIM * L_DIM)   // 4096
#define QKV_N  (3 * E_DIM)       // 3072
#define C_CONST 2.01f
#define NCH_BH 40                // chunks per bh at QBLK=128
#define LOG2E 1.4426950408889634f
#define LN2   0.6931471805599453f

typedef unsigned short ushort_t;
typedef __attribute__((ext_vector_type(8))) short bf16x8;
typedef __attribute__((ext_vector_type(4))) float f32x4;

__device__ __forceinline__ unsigned int f2bf(float f) {
    union { float f; unsigned int u; } v; v.f = f;
    return (v.u + 0x7FFFu + ((v.u >> 16) & 1u)) >> 16;   // RNE
}
__device__ __forceinline__ float bf2f_lo(unsigned int u) {
    union { unsigned int u; float f; } v; v.u = u << 16; return v.f;
}
__device__ __forceinline__ float bf2f_hi(unsigned int u) {
    union { unsigned int u; float f; } v; v.u = u & 0xffff0000u; return v.f;
}

__device__ __forceinline__ void gload16(const void* g, void* l) {
    __builtin_amdgcn_global_load_lds(
        (const __attribute__((address_space(1))) void*)g,
        (__attribute__((address_space(3))) void*)l, 16, 0, 0);
}

// ---------------------------------------------------------------------------
// prep: merged cast(x->bf16) + transpose(Wqkv) + transpose(Wout).
// ---------------------------------------------------------------------------
__device__ __forceinline__ void transpose_tile_dev(
    const float* __restrict__ in, ushort_t* __restrict__ out,
    int R, int Cn, int c0, int r0, int tid, float t[64][65])
{
    for (int idx = tid; idx < 4096; idx += 256) {
        const int r = idx >> 6, c = idx & 63;
        t[r][c] = in[(size_t)(r0 + r) * Cn + c0 + c];
    }
    __syncthreads();
    for (int idx = tid; idx < 4096; idx += 256) {
        const int c = idx >> 6, r = idx & 63;
        out[(size_t)(c0 + c) * R + r0 + r] = (ushort_t)f2bf(t[r][c]);
    }
}

__global__ __launch_bounds__(256) void prep_kernel(
    const float* __restrict__ x, ushort_t* __restrict__ xb,
    const float* __restrict__ Wqkv, ushort_t* __restrict__ WqkvT,
    const float* __restrict__ Wout, ushort_t* __restrict__ WoutT)
{
    __shared__ float t[64][65];
    const int bx = blockIdx.x;
    const int tid = threadIdx.x;
    if (bx < 4096) {
        const int i = bx * 256 + tid;
        const float4 v = ((const float4*)x)[i];
        uint2 p;
        p.x = f2bf(v.x) | (f2bf(v.y) << 16);
        p.y = f2bf(v.z) | (f2bf(v.w) << 16);
        ((uint2*)xb)[i] = p;
    } else if (bx < 4096 + 768) {
        const int idx = bx - 4096;
        transpose_tile_dev(Wqkv, WqkvT, E_DIM, QKV_N, (idx % 48) * 64, (idx / 48) * 64, tid, t);
    } else {
        const int idx = bx - 4864;
        transpose_tile_dev(Wout, WoutT, E_DIM, E_DIM, (idx & 15) * 64, (idx >> 4) * 64, tid, t);
    }
}

// ---------------------------------------------------------------------------
// bf16 MFMA GEMM, 128x128 tile, BK=32, 4 waves, single-buffer drain loop
// (measured-best; bracketed by 5 failed variants: dbuf -40%, reordered-dbuf
// -42%, BK=64 -30%, swizzle 0%, BM=64 -20%).
// MODE 0: qkv; epilogue: q,k L2-normalized -> bf16 [bh][l][d];
//         v -> bf16 V^T [bh][d][key] directly.
// MODE 1: plain C+bias fp32 [M][E].
// ---------------------------------------------------------------------------
template<int NCOLS, int MODE>
__global__ __launch_bounds__(256) void gemm_bt_kernel(
    const ushort_t* __restrict__ A, const ushort_t* __restrict__ BT,
    const float* __restrict__ bias, float* __restrict__ outf,
    ushort_t* __restrict__ q16, ushort_t* __restrict__ k16,
    ushort_t* __restrict__ vt16)
{
    __shared__ __align__(16) ushort_t Abuf[128 * 32];
    __shared__ __align__(16) ushort_t Bbuf[128 * 32];
    const int tid = threadIdx.x;
    const int wave = tid >> 6, lane = tid & 63;
    const int m0 = blockIdx.x * 128, n0 = blockIdx.y * 128;
    const int wr = (wave >> 1) * 64, wc = (wave & 1) * 64;
    const int g = lane >> 4, l15 = lane & 15;

    f32x4 acc[4][4];
    #pragma unroll
    for (int i = 0; i < 4; ++i)
        #pragma unroll
        for (int j = 0; j < 4; ++j) acc[i][j] = f32x4{0.f, 0.f, 0.f, 0.f};

    const int sr = tid >> 2;
    const int sc = (tid & 3) * 8;
    const ushort_t* Asrc0 = A + (size_t)(m0 + sr) * 1024 + sc;
    const ushort_t* Asrc1 = A + (size_t)(m0 + 64 + sr) * 1024 + sc;
    const ushort_t* Bsrc0 = BT + (size_t)(n0 + sr) * 1024 + sc;
    const ushort_t* Bsrc1 = BT + (size_t)(n0 + 64 + sr) * 1024 + sc;
    ushort_t* Adst0 = &Abuf[tid * 8];
    ushort_t* Adst1 = &Abuf[2048 + tid * 8];
    ushort_t* Bdst0 = &Bbuf[tid * 8];
    ushort_t* Bdst1 = &Bbuf[2048 + tid * 8];

    for (int k0 = 0; k0 < 1024; k0 += 32) {
        __syncthreads();                   // prior reads done
        gload16(Asrc0 + k0, Adst0);
        gload16(Asrc1 + k0, Adst1);
        gload16(Bsrc0 + k0, Bdst0);
        gload16(Bsrc1 + k0, Bdst1);
        __syncthreads();                   // staging drained (vmcnt 0 at barrier)

        bf16x8 af[4];
        #pragma unroll
        for (int mt = 0; mt < 4; ++mt)
            af[mt] = *(const bf16x8*)&Abuf[(wr + mt * 16 + l15) * 32 + 8 * g];
        #pragma unroll
        for (int nt = 0; nt < 4; ++nt) {
            const bf16x8 bfr = *(const bf16x8*)&Bbuf[(wc + nt * 16 + l15) * 32 + 8 * g];
            #pragma unroll
            for (int mt = 0; mt < 4; ++mt)
                acc[mt][nt] = __builtin_amdgcn_mfma_f32_16x16x32_bf16(af[mt], bfr, acc[mt][nt], 0, 0, 0);
        }
    }

    if (MODE == 0) {
        const int nBase = n0 + wc;
        const int sel = nBase >> 10;            // 0=q 1=k 2=v
        const int h   = (nBase & 1023) >> 6;
        float bv[4];
        #pragma unroll
        for (int nt = 0; nt < 4; ++nt) bv[nt] = bias[nBase + nt * 16 + l15];

        if (sel <= 1) {
            ushort_t* dst16 = (sel == 0) ? q16 : k16;
            #pragma unroll
            for (int mt = 0; mt < 4; ++mt) {
                float val[4][4], ss[4] = {0.f, 0.f, 0.f, 0.f};
                #pragma unroll
                for (int nt = 0; nt < 4; ++nt)
                    #pragma unroll
                    for (int r = 0; r < 4; ++r) {
                        const float v = acc[mt][nt][r] + bv[nt];
                        val[nt][r] = v;
                        ss[r] = fmaf(v, v, ss[r]);
                    }
                #pragma unroll
                for (int r = 0; r < 4; ++r) {
                    float t = ss[r];
                    t += __shfl_xor(t, 1); t += __shfl_xor(t, 2);
                    t += __shfl_xor(t, 4); t += __shfl_xor(t, 8);
                    ss[r] = 1.0f / sqrtf(t);
                }
                #pragma unroll
                for (int r = 0; r < 4; ++r) {
                    const int m = m0 + wr + mt * 16 + 4 * g + r;
                    const int bb = m >> 11, ll = m & 2047;
                    ushort_t* base = dst16 + ((size_t)((bb * H_DIM + h) * L_DIM + ll)) * HD + l15;
                    #pragma unroll
                    for (int nt = 0; nt < 4; ++nt)
                        base[nt * 16] = (ushort_t)f2bf(val[nt][r] * ss[r]);
                }
            }
        } else {
            // write V^T directly: vt16[(bb*H+h)*HD + d][key], 4 keys/store
            const int bb = m0 >> 11;
            #pragma unroll
            for (int nt = 0; nt < 4; ++nt) {
                const int d = nt * 16 + l15;
                ushort_t* vbase = vt16 + ((size_t)((bb * H_DIM + h) * HD + d)) * L_DIM;
                #pragma unroll
                for (int mt = 0; mt < 4; ++mt) {
                    const int key = (m0 & 2047) + wr + mt * 16 + 4 * g;
                    const float v0 = acc[mt][nt][0] + bv[nt];
                    const float v1 = acc[mt][nt][1] + bv[nt];
                    const float v2 = acc[mt][nt][2] + bv[nt];
                    const float v3 = acc[mt][nt][3] + bv[nt];
                    uint2 pk;
                    asm("v_cvt_pk_bf16_f32 %0, %1, %2" : "=v"(pk.x) : "v"(v0), "v"(v1));
                    asm("v_cvt_pk_bf16_f32 %0, %1, %2" : "=v"(pk.y) : "v"(v2), "v"(v3));
                    *(uint2*)&vbase[key] = pk;
                }
            }
        }
    } else {
        #pragma unroll
        for (int nt = 0; nt < 4; ++nt) {
            const int n = n0 + wc + nt * 16 + l15;
            const float bvv = bias[n];
            #pragma unroll
            for (int mt = 0; mt < 4; ++mt)
                #pragma unroll
                for (int r = 0; r < 4; ++r) {
                    const int m = m0 + wr + mt * 16 + 4 * g + r;
                    outf[(size_t)m * E_DIM + n] = acc[mt][nt][r] + bvv;
                }
        }
    }
}

// ---------------------------------------------------------------------------
// Split-K MFMA flash attention, QBLK=128, 8 waves (512 thr), kv tile 64.
// LPT dispatch (heavy chunks first). Log2-domain fixed-shift softmax.
// ---------------------------------------------------------------------------
__global__ __launch_bounds__(512) void attn_mfma_kernel(
    const ushort_t* __restrict__ qn, const ushort_t* __restrict__ kn,
    const ushort_t* __restrict__ vt,
    ushort_t* __restrict__ pO, float* __restrict__ pl, float* __restrict__ pm)
{
    __shared__ __align__(16) ushort_t Qs[128 * 64];     // Q; reused as P
    __shared__ __align__(16) ushort_t Ks[2][64 * 64];
    __shared__ __align__(16) ushort_t Vs[2][64 * 64];

    // LPT: reverse dispatch order (heavy qtp first); decode chunk -> (qt', s)
    const int cD = NCH_BH - 1 - blockIdx.x;
    int c = cD, qtp = 0, s = 0;
    #pragma unroll
    for (int gg = 0; gg < 4; ++gg) {
        const int sz = 4 * (gg + 1);
        if (c < sz) { qtp = 4 * gg + c / (gg + 1); s = c - (c / (gg + 1)) * (gg + 1); break; }
        c -= sz;
    }
    const int bh = blockIdx.y;
    const int cid = bh * NCH_BH + cD;
    const int q0 = qtp * 128;
    const int kt0 = 8 * s;
    const int ktEnd = min(8 * s + 8, 2 * qtp + 2);

    const int tid = threadIdx.x, w = tid >> 6, lane = tid & 63;
    const int g = lane >> 4, l15 = lane & 15;
    ushort_t* Pw = &Qs[w * 16 * 64];                // wave's own dead Q rows

    const ushort_t* Qg = qn + ((size_t)bh * L_DIM + q0) * HD;
    const ushort_t* Kg = kn + (size_t)bh * L_DIM * HD;
    const ushort_t* Vg = vt + (size_t)bh * HD * L_DIM;

    const int srow = tid >> 3, sch = tid & 7;
    const int qr2 = (tid + 512) >> 3, qc2 = (tid + 512) & 7;

    {
        const int j0 = kt0 * 64;
        gload16(Qg + srow * 64 + ((sch ^ (srow & 7)) << 3), Qs + srow * 64 + (sch << 3));
        gload16(Qg + qr2 * 64 + ((qc2 ^ (qr2 & 7)) << 3), Qs + qr2 * 64 + (qc2 << 3));
        gload16(Kg + (size_t)(j0 + srow) * 64 + ((sch ^ (srow & 7)) << 3), Ks[0] + srow * 64 + (sch << 3));
        gload16(Vg + (size_t)srow * L_DIM + j0 + ((sch ^ (srow & 7)) << 3), Vs[0] + srow * 64 + (sch << 3));
    }
    __syncthreads();

    bf16x8 qf[2];
    #pragma unroll
    for (int kc = 0; kc < 2; ++kc) {
        const int row = 16 * w + l15;
        qf[kc] = *(const bf16x8*)&Qs[row * 64 + (((4 * kc + g) ^ (row & 7)) << 3)];
    }

    f32x4 o[4];
    float M = 8.0f * LOG2E, l_i = 0.f;
    #pragma unroll
    for (int j = 0; j < 4; ++j) o[j] = f32x4{0.f, 0.f, 0.f, 0.f};

    const int qrow = q0 + 16 * w + l15;
    const float DC0 = 1.39322583292549f;      // C_CONST * ln2
    const float DC1 = -1.3862943611198906f;   // -2 * ln2

    for (int kt = kt0; kt < ktEnd; ++kt) {
        const int cur = (kt - kt0) & 1;
        if (kt + 1 < ktEnd) {
            const int j1 = (kt + 1) * 64;
            gload16(Kg + (size_t)(j1 + srow) * 64 + ((sch ^ (srow & 7)) << 3),
                    Ks[cur ^ 1] + srow * 64 + (sch << 3));
            gload16(Vg + (size_t)srow * L_DIM + j1 + ((sch ^ (srow & 7)) << 3),
                    Vs[cur ^ 1] + srow * 64 + (sch << 3));
        }
        const int j0 = kt * 64;

        // ---- S^T = K . Q^T ----
        bf16x8 ak[4][2];
        #pragma unroll
        for (int kt4 = 0; kt4 < 4; ++kt4)
            #pragma unroll
            for (int kc = 0; kc < 2; ++kc) {
                const int row = 16 * kt4 + l15;
                ak[kt4][kc] = *(const bf16x8*)&Ks[cur][row * 64 + (((4 * kc + g) ^ (row & 7)) << 3)];
            }
        f32x4 st[4];
        #pragma unroll
        for (int kt4 = 0; kt4 < 4; ++kt4) st[kt4] = f32x4{0.f, 0.f, 0.f, 0.f};
        __builtin_amdgcn_s_setprio(1);
        #pragma unroll
        for (int kc = 0; kc < 2; ++kc)
            #pragma unroll
            for (int kt4 = 0; kt4 < 4; ++kt4)
                st[kt4] = __builtin_amdgcn_mfma_f32_16x16x32_bf16(
                    ak[kt4][kc], qf[kc], st[kt4], 0, 0, 0);
        __builtin_amdgcn_s_setprio(0);

        // ---- score -> e (log2 domain, shifted by M); in-lane max ----
        const float negM = -M;
        float emax = -1e30f;
        #pragma unroll
        for (int kt4 = 0; kt4 < 4; ++kt4)
            #pragma unroll
            for (int r = 0; r < 4; ++r) {
                const float x = st[kt4][r];
                const float d = fmaf(DC1, x, DC0);
                float rr;
                asm("v_rcp_f32 %0, %1" : "=v"(rr) : "v"(d));
                const float e = fmaf(x * x, rr, negM);
                st[kt4][r] = e;
                emax = fmaxf(emax, e);
            }

        if (kt >= 2 * qtp) {   // diagonal region: mask, redo emax
            emax = -1e30f;
            #pragma unroll
            for (int kt4 = 0; kt4 < 4; ++kt4)
                #pragma unroll
                for (int r = 0; r < 4; ++r) {
                    const int key = j0 + 16 * kt4 + 4 * g + r;
                    float e = st[kt4][r];
                    e = (key > qrow) ? -100.f : e;
                    st[kt4][r] = e;
                    emax = fmaxf(emax, e);
                }
        }

        if (__any(emax > 0.f)) {
            float rm = fmaxf(emax, __shfl_xor(emax, 16));
            rm = fmaxf(rm, __shfl_xor(rm, 32));
            rm = fmaxf(rm, 0.f);
            #pragma unroll
            for (int kt4 = 0; kt4 < 4; ++kt4)
                #pragma unroll
                for (int r = 0; r < 4; ++r) st[kt4][r] -= rm;
            const float nrm = -rm;
            float scl;
            asm("v_exp_f32 %0, %1" : "=v"(scl) : "v"(nrm));
            l_i *= scl;
            #pragma unroll
            for (int r = 0; r < 4; ++r) {
                const float sv = __shfl(scl, 4 * g + r);
                #pragma unroll
                for (int dt = 0; dt < 4; ++dt) o[dt][r] *= sv;
            }
            M += rm;
        }

        // ---- p = exp2(e); per-lane partial sum; pack via cvt_pk ----
        float ts = 0.f;
        #pragma unroll
        for (int kt4 = 0; kt4 < 4; ++kt4) {
            const float e0 = st[kt4][0], e1 = st[kt4][1];
            const float e2 = st[kt4][2], e3 = st[kt4][3];
            float p0, p1, p2, p3;
            asm("v_exp_f32 %0, %1" : "=v"(p0) : "v"(e0));
            asm("v_exp_f32 %0, %1" : "=v"(p1) : "v"(e1));
            asm("v_exp_f32 %0, %1" : "=v"(p2) : "v"(e2));
            asm("v_exp_f32 %0, %1" : "=v"(p3) : "v"(e3));
            ts += (p0 + p1) + (p2 + p3);
            uint2 pk;
            asm("v_cvt_pk_bf16_f32 %0, %1, %2" : "=v"(pk.x) : "v"(p0), "v"(p1));
            asm("v_cvt_pk_bf16_f32 %0, %1, %2" : "=v"(pk.y) : "v"(p2), "v"(p3));
            const int ch = 2 * kt4 + (g >> 1);
            *(uint2*)&Pw[l15 * 64 + ((ch ^ (l15 & 7)) << 3) + 4 * (g & 1)] = pk;
        }
        l_i += ts;

        // ---- O += P . V ----
        bf16x8 ap[2], av[4][2];
        #pragma unroll
        for (int kc = 0; kc < 2; ++kc)
            ap[kc] = *(const bf16x8*)&Pw[l15 * 64 + (((4 * kc + g) ^ (l15 & 7)) << 3)];
        #pragma unroll
        for (int dt = 0; dt < 4; ++dt)
            #pragma unroll
            for (int kc = 0; kc < 2; ++kc) {
                const int row = 16 * dt + l15;
                av[dt][kc] = *(const bf16x8*)&Vs[cur][row * 64 + (((4 * kc + g) ^ (row & 7)) << 3)];
            }
        __builtin_amdgcn_s_setprio(1);
        #pragma unroll
        for (int kc = 0; kc < 2; ++kc)
            #pragma unroll
            for (int dt = 0; dt < 4; ++dt)
                o[dt] = __builtin_amdgcn_mfma_f32_16x16x32_bf16(
                    ap[kc], av[dt][kc], o[dt], 0, 0, 0);
        __builtin_amdgcn_s_setprio(0);

        __syncthreads();
    }

    // ---- epilogue: write partials; pm in natural-log domain ----
    l_i += __shfl_xor(l_i, 16);
    l_i += __shfl_xor(l_i, 32);
    ushort_t* po = pO + (size_t)cid * 8192 + (16 * w) * 64;
    #pragma unroll
    for (int r = 0; r < 4; ++r)
        #pragma unroll
        for (int dt = 0; dt < 4; ++dt)
            po[(4 * g + r) * 64 + 16 * dt + l15] = (ushort_t)f2bf(o[dt][r]);
    if (lane < 16) {
        pl[cid * 128 + 16 * w + lane] = l_i;
        pm[cid * 128 + 16 * w + lane] = M * LN2;
    }
}

// ---------------------------------------------------------------------------
// combine: merge <=4 chunk partials per 64-row output tile; write cb bf16
// ---------------------------------------------------------------------------
__global__ __launch_bounds__(256) void combine_kernel(
    const ushort_t* __restrict__ pO, const float* __restrict__ pl,
    const float* __restrict__ pm, ushort_t* __restrict__ cb)
{
    const int qt2 = blockIdx.x, bh = blockIdx.y;
    const int qtp = qt2 >> 1, half = qt2 & 1;
    const int gg = qtp >> 2, ns = gg + 1;
    const int cid0 = bh * NCH_BH + 2 * gg * (gg + 1) + (qtp & 3) * ns;
    const int tid = threadIdx.x;
    const int row = tid >> 2, seg = tid & 3;
    const int rowc = half * 64 + row;

    float mt = -1e30f;
    for (int s2 = 0; s2 < ns; ++s2)
        mt = fmaxf(mt, pm[(cid0 + s2) * 128 + rowc]);

    float acc[16];
    #pragma unroll
    for (int j = 0; j < 16; ++j) acc[j] = 0.f;
    float l_tot = 0.f;
    for (int s2 = 0; s2 < ns; ++s2) {
        const int cid = cid0 + s2;
        const float sc = __expf(pm[cid * 128 + rowc] - mt);
        l_tot += pl[cid * 128 + rowc] * sc;
        const ushort_t* src = pO + (size_t)cid * 8192 + rowc * 64 + seg * 16;
        const uint4 u0 = *(const uint4*)src;
        const uint4 u1 = *(const uint4*)(src + 8);
        const unsigned int uu[8] = {u0.x, u0.y, u0.z, u0.w, u1.x, u1.y, u1.z, u1.w};
        #pragma unroll
        for (int j = 0; j < 8; ++j) {
            acc[2 * j]     = fmaf(sc, bf2f_lo(uu[j]), acc[2 * j]);
            acc[2 * j + 1] = fmaf(sc, bf2f_hi(uu[j]), acc[2 * j + 1]);
        }
    }
    const float inv = 1.0f / l_tot;
    const int b = bh >> 4, h = bh & 15;
    ushort_t* dst = cb + ((size_t)(b * L_DIM + qt2 * 64 + row)) * E_DIM + h * HD + seg * 16;
    uint4 w0, w1;
    w0.x = f2bf(acc[0] * inv)  | (f2bf(acc[1] * inv) << 16);
    w0.y = f2bf(acc[2] * inv)  | (f2bf(acc[3] * inv) << 16);
    w0.z = f2bf(acc[4] * inv)  | (f2bf(acc[5] * inv) << 16);
    w0.w = f2bf(acc[6] * inv)  | (f2bf(acc[7] * inv) << 16);
    w1.x = f2bf(acc[8] * inv)  | (f2bf(acc[9] * inv) << 16);
    w1.y = f2bf(acc[10] * inv) | (f2bf(acc[11] * inv) << 16);
    w1.z = f2bf(acc[12] * inv) | (f2bf(acc[13] * inv) << 16);
    w1.w = f2bf(acc[14] * inv) | (f2bf(acc[15] * inv) << 16);
    *(uint4*)dst = w0;
    *(uint4*)(dst + 8) = w1;
}

// ---------------------------------------------------------------------------
extern "C" void kernel_launch(void* const* d_in, const int* in_sizes, int n_in,
                              void* d_out, int out_size, void* d_ws, size_t ws_size,
                              hipStream_t stream)
{
    const float* x    = (const float*)d_in[0];
    const float* Wqkv = (const float*)d_in[1];
    const float* bqkv = (const float*)d_in[2];
    const float* Wout = (const float*)d_in[3];
    const float* bout = (const float*)d_in[4];
    float* out = (float*)d_out;

    char* ws = (char*)d_ws;
    const size_t MB = 1u << 20;
    ushort_t* qn16  = (ushort_t*)(ws + 0 * MB);    // [0,8)
    ushort_t* kn16  = (ushort_t*)(ws + 8 * MB);    // [8,16)
    ushort_t* vt16  = (ushort_t*)(ws + 24 * MB);   // [24,32)
    ushort_t* xb    = (ushort_t*)(ws + 32 * MB);   // [32,40) dead after qkv gemm
    ushort_t* cb    = (ushort_t*)(ws + 32 * MB);   // reuse xb slot
    ushort_t* WqkvT = (ushort_t*)(ws + 40 * MB);   // [40,46) dead after qkv gemm
    ushort_t* pO    = (ushort_t*)(ws + 40 * MB);   // [40,60) 1280 x 16KB = 20 MB
    float*    pl    = (float*)   (ws + 60 * MB);   // [60,60.625)
    float*    pm    = (float*)   (ws + 61 * MB);   // [61,61.625)
    ushort_t* WoutT = (ushort_t*)(ws + 62 * MB);   // [62,64)

    // 1) merged prep: cast x + transpose Wqkv + transpose Wout
    prep_kernel<<<5120, 256, 0, stream>>>(x, xb, Wqkv, WqkvT, Wout, WoutT);

    // 2) qkv GEMM (measured-best drain loop) + fused normalize + V^T
    gemm_bt_kernel<QKV_N, 0><<<dim3(M_ROWS / 128, QKV_N / 128), 256, 0, stream>>>(
        xb, WqkvT, bqkv, nullptr, qn16, kn16, vt16);

    // 3) split-K MFMA flash attention (QBLK=128, 8 waves, LPT) -> partials
    attn_mfma_kernel<<<dim3(NCH_BH, B_DIM * H_DIM), 512, 0, stream>>>(qn16, kn16, vt16, pO, pl, pm);

    // 4) combine partials -> cb [M][E] bf16
    combine_kernel<<<dim3(L_DIM / 64, B_DIM * H_DIM), 256, 0, stream>>>(pO, pl, pm, cb);

    // 5) out = ctx @ W_out + b (measured-best drain loop)
    gemm_bt_kernel<E_DIM, 1><<<dim3(M_ROWS / 128, E_DIM / 128), 256, 0, stream>>>(
        cb, WoutT, bout, out, nullptr, nullptr, nullptr);
}